// Round 3
// baseline (641.994 us; speedup 1.0000x reference)
//
#include <hip/hip_runtime.h>
#include <hip/hip_bf16.h>
#include <stdint.h>

#define TOKENS 8192
#define D_IN   2048
#define D_OUT  8192
#define BK     64
#define NT     (D_IN / BK)   // 32 K-tiles

typedef __attribute__((ext_vector_type(8))) short short8;
typedef __attribute__((ext_vector_type(4))) float floatx4;

// async global->LDS, 16B per lane. LDS dest is wave-uniform base + lane*16.
__device__ __forceinline__ void async_copy16(const void* g, void* l) {
    __builtin_amdgcn_global_load_lds((const __attribute__((address_space(1))) void*)g,
                                     (__attribute__((address_space(3))) void*)l,
                                     16, 0, 0);
}

// ---------------------------------------------------------------------------
// FWHT over last dim (2048) of x [8192,2048] fp32 -> bf16 x_h in workspace.
// ---------------------------------------------------------------------------
__device__ __forceinline__ void fwht8(float* e) {
#pragma unroll
    for (int s = 1; s < 8; s <<= 1) {
#pragma unroll
        for (int j = 0; j < 8; ++j) {
            if ((j & s) == 0) {
                float a = e[j], b = e[j | s];
                e[j]     = a + b;
                e[j | s] = a - b;
            }
        }
    }
}

__global__ __launch_bounds__(256) void fwht_kernel(const float* __restrict__ x,
                                                   __hip_bfloat16* __restrict__ xh) {
    __shared__ float row[D_IN];
    const int r = blockIdx.x;
    const int t = threadIdx.x;
    const float* xr = x + (size_t)r * D_IN;

    float e[8];
#pragma unroll
    for (int j = 0; j < 8; ++j) e[j] = xr[t + 256 * j];
    fwht8(e);
#pragma unroll
    for (int j = 0; j < 8; ++j) row[t + 256 * j] = e[j];
    __syncthreads();

    float f[8];
#pragma unroll
    for (int j = 0; j < 8; ++j) f[j] = row[8 * t + j];
    fwht8(f);
#pragma unroll
    for (int m = 1; m <= 16; m <<= 1) {
#pragma unroll
        for (int j = 0; j < 8; ++j) {
            float v = __shfl_xor(f[j], m, 64);
            f[j] = (t & m) ? (v - f[j]) : (f[j] + v);
        }
    }

    const float scale = 0.02209708691207961f;  // 1/sqrt(2048)
    __hip_bfloat16 ob[8];
#pragma unroll
    for (int j = 0; j < 8; ++j) ob[j] = __float2bfloat16(f[j] * scale);
    __hip_bfloat16* orow = xh + (size_t)r * D_IN + 8 * t;
    *reinterpret_cast<int4*>(orow) = *reinterpret_cast<int4*>(ob);
}

// ---------------------------------------------------------------------------
// Weight fp32 -> bf16 (exact: w values are fp8-e4m3 representable).
// ---------------------------------------------------------------------------
__global__ __launch_bounds__(256) void wconv_kernel(const float* __restrict__ w,
                                                    __hip_bfloat16* __restrict__ wb) {
    const size_t i = ((size_t)blockIdx.x * 256 + threadIdx.x) * 8;
    float4 a = *reinterpret_cast<const float4*>(w + i);
    float4 b = *reinterpret_cast<const float4*>(w + i + 4);
    __hip_bfloat16 ob[8];
    ob[0] = __float2bfloat16(a.x); ob[1] = __float2bfloat16(a.y);
    ob[2] = __float2bfloat16(a.z); ob[3] = __float2bfloat16(a.w);
    ob[4] = __float2bfloat16(b.x); ob[5] = __float2bfloat16(b.y);
    ob[6] = __float2bfloat16(b.z); ob[7] = __float2bfloat16(b.w);
    *reinterpret_cast<int4*>(wb + i) = *reinterpret_cast<int4*>(ob);
}

// ---------------------------------------------------------------------------
// GEMM: C[t,o] = sum_d A[t,d]*B[o,d] + bias[o].  A=x_h bf16, B=w bf16.
// 256x256 tile, BK=64, 512 thr (8 waves, 2x4), wave tile 128x64.
// LDS 128KB: 2 dbuf x (A 32KB + B 32KB). Chunk-XOR swizzle (verified
// SQ_LDS_BANK_CONFLICT=0). 2D patch XCD swizzle. Plain C stores (NT stores
// regressed in round 2: +85MB write amplification).
//
// ROUND 3: Gray-code phase order + ds_read READ-AHEAD. Round-2 counters
// showed MfmaUtil capped at 42% because each phase's 12/8/4 ds_reads were
// issued in the phase that consumes them -> lgkmcnt serializes LDS-read
// time (~2260 cyc/CU/tile) with MFMA time (~2480 cyc). Now every fragment
// group is loaded into DEAD registers 1-3 phases before first use, so the
// LDS pipe runs under the MFMA clusters and every MFMA cluster's lgkm wait
// is ~0. No extra VGPRs (no frag double-buffer needed).
//
// Quadrants: ph0:(m0-3,n0-1) ph1:(m0-3,n2-3) ph2:(m4-7,n2-3) ph3:(m4-7,n0-1)
// Issue plan per tile kt (cur = buf kt&1, nxt = buf (kt+1)&1):
//  ph0: read af47(kt) [cur, used ph2/ph3]; stage B(kt+1,h0)->nxt; MFMA0
//  ph1: stage B(kt+1,h1)->nxt; MFMA1
//  ph2: stage A(kt+2,h0)->cur; vmcnt(2|0) [drains A(kt+1)+B(kt+1)];
//       barrier; read af03(kt+1) [nxt, used next ph0/ph1]; MFMA2
//  ph3: stage A(kt+2,h1)->cur; read bf23(kt+1) [nxt]; MFMA3;
//       read bf01(kt+1) [nxt, after MFMA3 consumed old bf01 (reg WAR)]
// Single counted vmcnt per tile, at ph2; never a drain-to-0 in steady state.
// Edge kt=NT-2: without A(kt+2) staged, vmcnt(2) would leave B(kt+1,h1)
// in flight -> use vmcnt(0) when kt+2>=NT (tail only).
// ---------------------------------------------------------------------------
__global__ __launch_bounds__(512, 2) void gemm_kernel(const __hip_bfloat16* __restrict__ A,
                                                      const __hip_bfloat16* __restrict__ B,
                                                      const float* __restrict__ bias,
                                                      float* __restrict__ C) {
    extern __shared__ float4 smem_f4[];
    __hip_bfloat16* sA = (__hip_bfloat16*)smem_f4;           // [2][256][64]
    __hip_bfloat16* sB = sA + 2 * 16384;                     // [2][256][64]

    const int tid    = threadIdx.x;
    const int wave   = tid >> 6;
    const int lane   = tid & 63;
    const int lane16 = lane & 15;
    const int lgrp   = lane >> 4;

    // 2D patch XCD swizzle (bijective): XCD x owns bm in [4x,4x+4); rounds
    // sweep bn in groups of 8 -> co-resident 4x8 patch per XCD L2.
    const int bid = blockIdx.x;
    const int xcd = bid & 7;
    const int loc = bid >> 3;        // 0..127
    const int rnd = loc >> 5;        // 0..3
    const int pos = loc & 31;
    const int bm  = xcd * 4 + (pos >> 3);   // 0..31
    const int bn  = rnd * 8 + (pos & 7);    // 0..31

    const int wm = wave >> 2; // 0..1
    const int wn = wave & 3;  // 0..3

    // ---- staging geometry (2 gload_lds per half-tile per thread) ----
    const int srow = lane >> 3;                 // 0..7
    const int scc8 = ((lane & 7) ^ srow) * 8;   // pre-swizzled source chunk
    const int r0   = wave * 16 + srow;          // instr-0 row within 128-row half
    const __hip_bfloat16* gAst = A + (size_t)(bm * 256) * D_IN + scc8;
    const __hip_bfloat16* gBst = B + (size_t)(bn * 256) * D_IN + scc8;

    auto stageA = [&](int kt, int h) {
        const __hip_bfloat16* g = gAst + (size_t)(h * 128 + r0) * D_IN + kt * BK;
        __hip_bfloat16* l = sA + (kt & 1) * 16384 + h * 8192 + wave * 1024;
        async_copy16(g, l);
        async_copy16(g + (size_t)8 * D_IN, l + 512);
    };
    auto stageB = [&](int kt, int h) {
        const __hip_bfloat16* g = gBst + (size_t)(h * 128 + r0) * D_IN + kt * BK;
        __hip_bfloat16* l = sB + (kt & 1) * 16384 + h * 8192 + wave * 1024;
        async_copy16(g, l);
        async_copy16(g + (size_t)8 * D_IN, l + 512);
    };

    // ---- ds_read fragment geometry (swizzled chunk, conflict-free) ----
    const int sw   = lane16 & 7;
    const int cK0  = ((0 + lgrp) ^ sw) * 8;   // kk=0 chunk elem offset
    const int cK1  = ((4 + lgrp) ^ sw) * 8;   // kk=1 chunk elem offset
    const int arow = wm * 128 + lane16;       // + m*16
    const int brow = wn * 64  + lane16;       // + n*16

    floatx4 acc[8][4];
#pragma unroll
    for (int m = 0; m < 8; ++m)
#pragma unroll
        for (int n = 0; n < 4; ++n) acc[m][n] = 0;

    // ---- prologue: A0, B0, A1 staged; vmcnt(4) drains A0+B0 (A1 in flight);
    //      preload af03(0), bf23(0), bf01(0) so tile-0 ph0 starts hot.
    stageA(0, 0); stageA(0, 1);
    stageB(0, 0); stageB(0, 1);
    stageA(1, 0); stageA(1, 1);
    asm volatile("s_waitcnt vmcnt(4)" ::: "memory");
    asm volatile("s_barrier" ::: "memory");

    short8 af[8][2];
    short8 bf[4][2];
#pragma unroll
    for (int m = 0; m < 4; ++m) {
        const __hip_bfloat16* p = sA + (arow + m * 16) * 64;
        af[m][0] = *reinterpret_cast<const short8*>(p + cK0);
        af[m][1] = *reinterpret_cast<const short8*>(p + cK1);
    }
#pragma unroll
    for (int n = 0; n < 4; ++n) {
        const __hip_bfloat16* p = sB + (brow + n * 16) * 64;
        bf[n][0] = *reinterpret_cast<const short8*>(p + cK0);
        bf[n][1] = *reinterpret_cast<const short8*>(p + cK1);
    }

#pragma unroll 2
    for (int kt = 0; kt < NT; ++kt) {
        const __hip_bfloat16* curA = sA + ((kt & 1) << 14);
        const __hip_bfloat16* nxtA = sA + (((kt + 1) & 1) << 14);
        const __hip_bfloat16* nxtB = sB + (((kt + 1) & 1) << 14);

        // ==== ph0: read-ahead af47(kt); stage B(kt+1,h0); MFMA m0-3 x n0-1
#pragma unroll
        for (int m = 4; m < 8; ++m) {
            const __hip_bfloat16* p = curA + (arow + m * 16) * 64;
            af[m][0] = *reinterpret_cast<const short8*>(p + cK0);
            af[m][1] = *reinterpret_cast<const short8*>(p + cK1);
        }
        if (kt + 1 < NT) stageB(kt + 1, 0);
        asm volatile("s_barrier" ::: "memory");
        __builtin_amdgcn_s_setprio(1);
#pragma unroll
        for (int m = 0; m < 4; ++m)
#pragma unroll
            for (int n = 0; n < 2; ++n) {
                acc[m][n] = __builtin_amdgcn_mfma_f32_16x16x32_bf16(af[m][0], bf[n][0], acc[m][n], 0, 0, 0);
                acc[m][n] = __builtin_amdgcn_mfma_f32_16x16x32_bf16(af[m][1], bf[n][1], acc[m][n], 0, 0, 0);
            }
        __builtin_amdgcn_s_setprio(0);
        asm volatile("s_barrier" ::: "memory");

        // ==== ph1: stage B(kt+1,h1); MFMA m0-3 x n2-3 (all frags resident)
        if (kt + 1 < NT) stageB(kt + 1, 1);
        asm volatile("s_barrier" ::: "memory");
        __builtin_amdgcn_s_setprio(1);
#pragma unroll
        for (int m = 0; m < 4; ++m)
#pragma unroll
            for (int n = 2; n < 4; ++n) {
                acc[m][n] = __builtin_amdgcn_mfma_f32_16x16x32_bf16(af[m][0], bf[n][0], acc[m][n], 0, 0, 0);
                acc[m][n] = __builtin_amdgcn_mfma_f32_16x16x32_bf16(af[m][1], bf[n][1], acc[m][n], 0, 0, 0);
            }
        __builtin_amdgcn_s_setprio(0);
        asm volatile("s_barrier" ::: "memory");

        // ==== ph2: stage A(kt+2,h0); counted vmcnt; barrier;
        //           read-ahead af03(kt+1); MFMA m4-7 x n2-3
        if (kt + 2 < NT) {
            stageA(kt + 2, 0);
            asm volatile("s_waitcnt vmcnt(2)" ::: "memory");  // drains A(kt+1)+B(kt+1)
        } else {
            asm volatile("s_waitcnt vmcnt(0)" ::: "memory");  // tail drain
        }
        asm volatile("s_barrier" ::: "memory");
        if (kt + 1 < NT) {
#pragma unroll
            for (int m = 0; m < 4; ++m) {
                const __hip_bfloat16* p = nxtA + (arow + m * 16) * 64;
                af[m][0] = *reinterpret_cast<const short8*>(p + cK0);
                af[m][1] = *reinterpret_cast<const short8*>(p + cK1);
            }
        }
        __builtin_amdgcn_s_setprio(1);
#pragma unroll
        for (int m = 4; m < 8; ++m)
#pragma unroll
            for (int n = 2; n < 4; ++n) {
                acc[m][n] = __builtin_amdgcn_mfma_f32_16x16x32_bf16(af[m][0], bf[n][0], acc[m][n], 0, 0, 0);
                acc[m][n] = __builtin_amdgcn_mfma_f32_16x16x32_bf16(af[m][1], bf[n][1], acc[m][n], 0, 0, 0);
            }
        __builtin_amdgcn_s_setprio(0);
        asm volatile("s_barrier" ::: "memory");

        // ==== ph3: stage A(kt+2,h1); read-ahead bf23(kt+1); MFMA m4-7 x n0-1;
        //           read-ahead bf01(kt+1) after MFMA3 (reg WAR orders it)
        if (kt + 2 < NT) stageA(kt + 2, 1);
        if (kt + 1 < NT) {
#pragma unroll
            for (int n = 2; n < 4; ++n) {
                const __hip_bfloat16* p = nxtB + (brow + n * 16) * 64;
                bf[n][0] = *reinterpret_cast<const short8*>(p + cK0);
                bf[n][1] = *reinterpret_cast<const short8*>(p + cK1);
            }
        }
        asm volatile("s_barrier" ::: "memory");
        __builtin_amdgcn_s_setprio(1);
#pragma unroll
        for (int m = 4; m < 8; ++m)
#pragma unroll
            for (int n = 0; n < 2; ++n) {
                acc[m][n] = __builtin_amdgcn_mfma_f32_16x16x32_bf16(af[m][0], bf[n][0], acc[m][n], 0, 0, 0);
                acc[m][n] = __builtin_amdgcn_mfma_f32_16x16x32_bf16(af[m][1], bf[n][1], acc[m][n], 0, 0, 0);
            }
        __builtin_amdgcn_s_setprio(0);
        if (kt + 1 < NT) {
#pragma unroll
            for (int n = 0; n < 2; ++n) {
                const __hip_bfloat16* p = nxtB + (brow + n * 16) * 64;
                bf[n][0] = *reinterpret_cast<const short8*>(p + cK0);
                bf[n][1] = *reinterpret_cast<const short8*>(p + cK1);
            }
        }
        asm volatile("s_barrier" ::: "memory");
    }

    // ---- epilogue: C/D layout col=lane&15, row=lgrp*4+r. Plain stores. ----
    float bv[4];
#pragma unroll
    for (int n = 0; n < 4; ++n) bv[n] = bias[bn * 256 + wn * 64 + n * 16 + lane16];

#pragma unroll
    for (int m = 0; m < 8; ++m) {
        const int rbase = bm * 256 + wm * 128 + m * 16 + lgrp * 4;
#pragma unroll
        for (int n = 0; n < 4; ++n) {
            const int col = bn * 256 + wn * 64 + n * 16 + lane16;
#pragma unroll
            for (int r = 0; r < 4; ++r) {
                C[(size_t)(rbase + r) * D_OUT + col] = acc[m][n][r] + bv[n];
            }
        }
    }
}

extern "C" void kernel_launch(void* const* d_in, const int* in_sizes, int n_in,
                              void* d_out, int out_size, void* d_ws, size_t ws_size,
                              hipStream_t stream) {
    const float* x    = (const float*)d_in[0];
    const float* w    = (const float*)d_in[1];
    const float* bias = (const float*)d_in[2];
    float* out = (float*)d_out;

    __hip_bfloat16* xh = (__hip_bfloat16*)d_ws;                      // 32 MB
    __hip_bfloat16* wb = xh + (size_t)TOKENS * D_IN;                 // 32 MB

    static bool attr_set = false;
    if (!attr_set) {
        (void)hipFuncSetAttribute((const void*)gemm_kernel,
                                  hipFuncAttributeMaxDynamicSharedMemorySize, 131072);
        attr_set = true;
    }

    fwht_kernel<<<TOKENS, 256, 0, stream>>>(x, xh);
    wconv_kernel<<<(D_OUT * D_IN / 8) / 256, 256, 0, stream>>>(w, wb);
    gemm_kernel<<<1024, 512, 131072, stream>>>(xh, wb, bias, out);
}

// Round 4
// 554.527 us; speedup vs baseline: 1.1577x; 1.1577x over previous
//
#include <hip/hip_runtime.h>
#include <hip/hip_bf16.h>
#include <stdint.h>

#define TOKENS 8192
#define D_IN   2048
#define D_OUT  8192
#define BK     64
#define NT     (D_IN / BK)   // 32 K-tiles

typedef __attribute__((ext_vector_type(8))) short short8;
typedef __attribute__((ext_vector_type(4))) float floatx4;

// async global->LDS, 16B per lane. LDS dest is wave-uniform base + lane*16.
__device__ __forceinline__ void async_copy16(const void* g, void* l) {
    __builtin_amdgcn_global_load_lds((const __attribute__((address_space(1))) void*)g,
                                     (__attribute__((address_space(3))) void*)l,
                                     16, 0, 0);
}

// ---------------------------------------------------------------------------
// FWHT over last dim (2048) of x [8192,2048] fp32 -> bf16 x_h in workspace.
// ---------------------------------------------------------------------------
__device__ __forceinline__ void fwht8(float* e) {
#pragma unroll
    for (int s = 1; s < 8; s <<= 1) {
#pragma unroll
        for (int j = 0; j < 8; ++j) {
            if ((j & s) == 0) {
                float a = e[j], b = e[j | s];
                e[j]     = a + b;
                e[j | s] = a - b;
            }
        }
    }
}

__global__ __launch_bounds__(256) void fwht_kernel(const float* __restrict__ x,
                                                   __hip_bfloat16* __restrict__ xh) {
    __shared__ float row[D_IN];
    const int r = blockIdx.x;
    const int t = threadIdx.x;
    const float* xr = x + (size_t)r * D_IN;

    float e[8];
#pragma unroll
    for (int j = 0; j < 8; ++j) e[j] = xr[t + 256 * j];
    fwht8(e);
#pragma unroll
    for (int j = 0; j < 8; ++j) row[t + 256 * j] = e[j];
    __syncthreads();

    float f[8];
#pragma unroll
    for (int j = 0; j < 8; ++j) f[j] = row[8 * t + j];
    fwht8(f);
#pragma unroll
    for (int m = 1; m <= 16; m <<= 1) {
#pragma unroll
        for (int j = 0; j < 8; ++j) {
            float v = __shfl_xor(f[j], m, 64);
            f[j] = (t & m) ? (v - f[j]) : (f[j] + v);
        }
    }

    const float scale = 0.02209708691207961f;  // 1/sqrt(2048)
    __hip_bfloat16 ob[8];
#pragma unroll
    for (int j = 0; j < 8; ++j) ob[j] = __float2bfloat16(f[j] * scale);
    __hip_bfloat16* orow = xh + (size_t)r * D_IN + 8 * t;
    *reinterpret_cast<int4*>(orow) = *reinterpret_cast<int4*>(ob);
}

// ---------------------------------------------------------------------------
// Weight fp32 -> bf16 (exact: w values are fp8-e4m3 representable).
// ---------------------------------------------------------------------------
__global__ __launch_bounds__(256) void wconv_kernel(const float* __restrict__ w,
                                                    __hip_bfloat16* __restrict__ wb) {
    const size_t i = ((size_t)blockIdx.x * 256 + threadIdx.x) * 8;
    float4 a = *reinterpret_cast<const float4*>(w + i);
    float4 b = *reinterpret_cast<const float4*>(w + i + 4);
    __hip_bfloat16 ob[8];
    ob[0] = __float2bfloat16(a.x); ob[1] = __float2bfloat16(a.y);
    ob[2] = __float2bfloat16(a.z); ob[3] = __float2bfloat16(a.w);
    ob[4] = __float2bfloat16(b.x); ob[5] = __float2bfloat16(b.y);
    ob[6] = __float2bfloat16(b.z); ob[7] = __float2bfloat16(b.w);
    *reinterpret_cast<int4*>(wb + i) = *reinterpret_cast<int4*>(ob);
}

// ---------------------------------------------------------------------------
// GEMM: C[t,o] = sum_d A[t,d]*B[o,d] + bias[o].  A=x_h bf16, B=w bf16.
// 256x256 tile, BK=64, 512 thr (8 waves, 2x4), wave tile 128x64.
// LDS 128KB: 2 dbuf x (A 32KB + B 32KB). Chunk-XOR swizzle (verified
// SQ_LDS_BANK_CONFLICT=0). 2D patch XCD swizzle. Plain C stores.
//
// ROUND 4: RAW barriers. Rounds 1-3 used asm("s_barrier":::"memory");
// the "memory" clobber makes the compiler insert s_waitcnt vmcnt(0)
// lgkmcnt(0) before EVERY barrier -> full drain per phase (the m97
// structure), counted vmcnt dead, read-ahead useless. Now:
//   - __builtin_amdgcn_s_barrier() (no compiler drain),
//   - explicit asm lgkmcnt(0) + sched_barrier(0) before each MFMA cluster
//     (rule #18: hipcc hoists reg-only MFMA past inline-asm waits),
//   - ONE counted vmcnt(4) per K-tile at ph3-end (tail: vmcnt(0)).
// Wait accounting (per wave, 2 gload_lds per stage call):
//   tile-kt start: A(kt+1) in flight (4). ph0 +B(kt+1,h0), ph1 +B(kt+1,h1),
//   ph2 +A(kt+2,h0), ph3 +A(kt+2,h1) -> 12 outstanding; vmcnt(4) drains
//   A(kt+1)+B(kt+1), leaves A(kt+2) flying across the tile boundary.
//   kt=NT-2 has no A(kt+2) staged -> vmcnt(0) (tail only).
// Re-staging safety: stage A(kt+2,h0/h1) at ph2/ph3 overwrites cur-A rows
// read at ph0/ph1; every wave lgkm-drains its reads before its MFMA, hence
// before ph1-barrier-2; stages are issued after that barrier. No race.
// ---------------------------------------------------------------------------
__global__ __launch_bounds__(512, 2) void gemm_kernel(const __hip_bfloat16* __restrict__ A,
                                                      const __hip_bfloat16* __restrict__ B,
                                                      const float* __restrict__ bias,
                                                      float* __restrict__ C) {
    extern __shared__ float4 smem_f4[];
    __hip_bfloat16* sA = (__hip_bfloat16*)smem_f4;           // [2][256][64]
    __hip_bfloat16* sB = sA + 2 * 16384;                     // [2][256][64]

    const int tid    = threadIdx.x;
    const int wave   = tid >> 6;
    const int lane   = tid & 63;
    const int lane16 = lane & 15;
    const int lgrp   = lane >> 4;

    // 2D patch XCD swizzle (bijective): XCD x owns bm in [4x,4x+4); rounds
    // sweep bn in groups of 8 -> co-resident 4x8 patch per XCD L2.
    const int bid = blockIdx.x;
    const int xcd = bid & 7;
    const int loc = bid >> 3;        // 0..127
    const int rnd = loc >> 5;        // 0..3
    const int pos = loc & 31;
    const int bm  = xcd * 4 + (pos >> 3);   // 0..31
    const int bn  = rnd * 8 + (pos & 7);    // 0..31

    const int wm = wave >> 2; // 0..1
    const int wn = wave & 3;  // 0..3

    // ---- staging geometry (2 gload_lds per half-tile per thread) ----
    const int srow = lane >> 3;                 // 0..7
    const int scc8 = ((lane & 7) ^ srow) * 8;   // pre-swizzled source chunk
    const int r0   = wave * 16 + srow;          // instr-0 row within 128-row half
    const __hip_bfloat16* gAst = A + (size_t)(bm * 256) * D_IN + scc8;
    const __hip_bfloat16* gBst = B + (size_t)(bn * 256) * D_IN + scc8;

    auto stageA = [&](int kt, int h) {
        const __hip_bfloat16* g = gAst + (size_t)(h * 128 + r0) * D_IN + kt * BK;
        __hip_bfloat16* l = sA + (kt & 1) * 16384 + h * 8192 + wave * 1024;
        async_copy16(g, l);
        async_copy16(g + (size_t)8 * D_IN, l + 512);
    };
    auto stageB = [&](int kt, int h) {
        const __hip_bfloat16* g = gBst + (size_t)(h * 128 + r0) * D_IN + kt * BK;
        __hip_bfloat16* l = sB + (kt & 1) * 16384 + h * 8192 + wave * 1024;
        async_copy16(g, l);
        async_copy16(g + (size_t)8 * D_IN, l + 512);
    };

    // ---- ds_read fragment geometry (swizzled chunk, conflict-free) ----
    const int sw   = lane16 & 7;
    const int cK0  = ((0 + lgrp) ^ sw) * 8;   // kk=0 chunk elem offset
    const int cK1  = ((4 + lgrp) ^ sw) * 8;   // kk=1 chunk elem offset
    const int arow = wm * 128 + lane16;       // + m*16
    const int brow = wn * 64  + lane16;       // + n*16

    floatx4 acc[8][4];
#pragma unroll
    for (int m = 0; m < 8; ++m)
#pragma unroll
        for (int n = 0; n < 4; ++n) acc[m][n] = 0;

    // ---- prologue: A0, B0, A1 staged; vmcnt(4) drains A0+B0 (A1 in flight)
    stageA(0, 0); stageA(0, 1);
    stageB(0, 0); stageB(0, 1);
    stageA(1, 0); stageA(1, 1);
    __builtin_amdgcn_sched_barrier(0);
    asm volatile("s_waitcnt vmcnt(4)");
    __builtin_amdgcn_s_barrier();
    __builtin_amdgcn_sched_barrier(0);

    short8 af[8][2];
    short8 bf[4][2];

#pragma unroll 2
    for (int kt = 0; kt < NT; ++kt) {
        const __hip_bfloat16* curA = sA + ((kt & 1) << 14);
        const __hip_bfloat16* curB = sB + ((kt & 1) << 14);

        // ==== ph0: read af m0-3 + bf n0-1; stage B(kt+1,h0); MFMA (m0-3,n0-1)
#pragma unroll
        for (int m = 0; m < 4; ++m) {
            const __hip_bfloat16* p = curA + (arow + m * 16) * 64;
            af[m][0] = *reinterpret_cast<const short8*>(p + cK0);
            af[m][1] = *reinterpret_cast<const short8*>(p + cK1);
        }
#pragma unroll
        for (int n = 0; n < 2; ++n) {
            const __hip_bfloat16* p = curB + (brow + n * 16) * 64;
            bf[n][0] = *reinterpret_cast<const short8*>(p + cK0);
            bf[n][1] = *reinterpret_cast<const short8*>(p + cK1);
        }
        if (kt + 1 < NT) stageB(kt + 1, 0);
        __builtin_amdgcn_s_barrier();
        asm volatile("s_waitcnt lgkmcnt(0)");
        __builtin_amdgcn_sched_barrier(0);
        __builtin_amdgcn_s_setprio(1);
#pragma unroll
        for (int m = 0; m < 4; ++m)
#pragma unroll
            for (int n = 0; n < 2; ++n) {
                acc[m][n] = __builtin_amdgcn_mfma_f32_16x16x32_bf16(af[m][0], bf[n][0], acc[m][n], 0, 0, 0);
                acc[m][n] = __builtin_amdgcn_mfma_f32_16x16x32_bf16(af[m][1], bf[n][1], acc[m][n], 0, 0, 0);
            }
        __builtin_amdgcn_s_setprio(0);
        __builtin_amdgcn_s_barrier();

        // ==== ph1: read af m4-7; stage B(kt+1,h1); MFMA (m4-7,n0-1)
#pragma unroll
        for (int m = 4; m < 8; ++m) {
            const __hip_bfloat16* p = curA + (arow + m * 16) * 64;
            af[m][0] = *reinterpret_cast<const short8*>(p + cK0);
            af[m][1] = *reinterpret_cast<const short8*>(p + cK1);
        }
        if (kt + 1 < NT) stageB(kt + 1, 1);
        __builtin_amdgcn_s_barrier();
        asm volatile("s_waitcnt lgkmcnt(0)");
        __builtin_amdgcn_sched_barrier(0);
        __builtin_amdgcn_s_setprio(1);
#pragma unroll
        for (int m = 4; m < 8; ++m)
#pragma unroll
            for (int n = 0; n < 2; ++n) {
                acc[m][n] = __builtin_amdgcn_mfma_f32_16x16x32_bf16(af[m][0], bf[n][0], acc[m][n], 0, 0, 0);
                acc[m][n] = __builtin_amdgcn_mfma_f32_16x16x32_bf16(af[m][1], bf[n][1], acc[m][n], 0, 0, 0);
            }
        __builtin_amdgcn_s_setprio(0);
        __builtin_amdgcn_s_barrier();

        // ==== ph2: read bf n2-3; stage A(kt+2,h0); MFMA (m0-3,n2-3)
#pragma unroll
        for (int n = 2; n < 4; ++n) {
            const __hip_bfloat16* p = curB + (brow + n * 16) * 64;
            bf[n][0] = *reinterpret_cast<const short8*>(p + cK0);
            bf[n][1] = *reinterpret_cast<const short8*>(p + cK1);
        }
        if (kt + 2 < NT) stageA(kt + 2, 0);
        __builtin_amdgcn_s_barrier();
        asm volatile("s_waitcnt lgkmcnt(0)");
        __builtin_amdgcn_sched_barrier(0);
        __builtin_amdgcn_s_setprio(1);
#pragma unroll
        for (int m = 0; m < 4; ++m)
#pragma unroll
            for (int n = 2; n < 4; ++n) {
                acc[m][n] = __builtin_amdgcn_mfma_f32_16x16x32_bf16(af[m][0], bf[n][0], acc[m][n], 0, 0, 0);
                acc[m][n] = __builtin_amdgcn_mfma_f32_16x16x32_bf16(af[m][1], bf[n][1], acc[m][n], 0, 0, 0);
            }
        __builtin_amdgcn_s_setprio(0);
        __builtin_amdgcn_s_barrier();

        // ==== ph3: stage A(kt+2,h1); MFMA (m4-7,n2-3); counted vmcnt; barrier
        if (kt + 2 < NT) stageA(kt + 2, 1);
        __builtin_amdgcn_s_barrier();
        asm volatile("s_waitcnt lgkmcnt(0)");
        __builtin_amdgcn_sched_barrier(0);
        __builtin_amdgcn_s_setprio(1);
#pragma unroll
        for (int m = 4; m < 8; ++m)
#pragma unroll
            for (int n = 2; n < 4; ++n) {
                acc[m][n] = __builtin_amdgcn_mfma_f32_16x16x32_bf16(af[m][0], bf[n][0], acc[m][n], 0, 0, 0);
                acc[m][n] = __builtin_amdgcn_mfma_f32_16x16x32_bf16(af[m][1], bf[n][1], acc[m][n], 0, 0, 0);
            }
        __builtin_amdgcn_s_setprio(0);
        __builtin_amdgcn_sched_barrier(0);
        if (kt + 2 < NT) {
            asm volatile("s_waitcnt vmcnt(4)");   // drains A(kt+1)+B(kt+1); A(kt+2) stays in flight
        } else {
            asm volatile("s_waitcnt vmcnt(0)");   // tail drain (kt=NT-2, NT-1)
        }
        __builtin_amdgcn_s_barrier();
        __builtin_amdgcn_sched_barrier(0);
    }

    // ---- epilogue: C/D layout col=lane&15, row=lgrp*4+r. Plain stores. ----
    float bv[4];
#pragma unroll
    for (int n = 0; n < 4; ++n) bv[n] = bias[bn * 256 + wn * 64 + n * 16 + lane16];

#pragma unroll
    for (int m = 0; m < 8; ++m) {
        const int rbase = bm * 256 + wm * 128 + m * 16 + lgrp * 4;
#pragma unroll
        for (int n = 0; n < 4; ++n) {
            const int col = bn * 256 + wn * 64 + n * 16 + lane16;
#pragma unroll
            for (int r = 0; r < 4; ++r) {
                C[(size_t)(rbase + r) * D_OUT + col] = acc[m][n][r] + bv[n];
            }
        }
    }
}

extern "C" void kernel_launch(void* const* d_in, const int* in_sizes, int n_in,
                              void* d_out, int out_size, void* d_ws, size_t ws_size,
                              hipStream_t stream) {
    const float* x    = (const float*)d_in[0];
    const float* w    = (const float*)d_in[1];
    const float* bias = (const float*)d_in[2];
    float* out = (float*)d_out;

    __hip_bfloat16* xh = (__hip_bfloat16*)d_ws;                      // 32 MB
    __hip_bfloat16* wb = xh + (size_t)TOKENS * D_IN;                 // 32 MB

    static bool attr_set = false;
    if (!attr_set) {
        (void)hipFuncSetAttribute((const void*)gemm_kernel,
                                  hipFuncAttributeMaxDynamicSharedMemorySize, 131072);
        attr_set = true;
    }

    fwht_kernel<<<TOKENS, 256, 0, stream>>>(x, xh);
    wconv_kernel<<<(D_OUT * D_IN / 8) / 256, 256, 0, stream>>>(w, wb);
    gemm_kernel<<<1024, 512, 131072, stream>>>(xh, wb, bias, out);
}